// Round 2
// baseline (1077.984 us; speedup 1.0000x reference)
//
#include <hip/hip_runtime.h>
#include <stdint.h>

// LSTMNet: B=2048, T=512, IN=64, H=64, 4H=256, 2 layers, FC to 4 classes.
// 256 WGs x 512 threads; WG owns 8 batches through both layers, all 512 steps.
// Weights resident in registers as MFMA B-fragments (hi+lo bf16 split).
// Precision: "hi/lo-in-M" bf16x4 — A rows 0-7 = bf16_hi, rows 8-15 = bf16_lo;
// two B passes (W_hi, W_lo); fold C rows m + m+8 => fp32-grade.
// R2: merged 2-barrier pipeline — one MFMA phase computes L1(t)+L0(t+1)
// (4 indep accumulator chains), one elementwise phase does both cell updates.
// Hi/lo C-fold via __shfl_xor(32) in-register; A-frags via ds_read_b128.

#define T_SEQ 512
#define NB    8            // batches per workgroup
#define PSTR  136          // A-panel row stride (bf16): 272B -> 16B-aligned b128 reads
#define GSTR  257          // gate buffer row stride (f32)

typedef __attribute__((ext_vector_type(8))) short  short8;   // 8 x bf16 (4 VGPRs)
typedef __attribute__((ext_vector_type(4))) float  float4v;  // MFMA C/D

__device__ __forceinline__ unsigned short f2bf(float f) {
    unsigned int u = __builtin_bit_cast(unsigned int, f);
    return (unsigned short)((u + 0x7FFFu + ((u >> 16) & 1u)) >> 16);  // RNE
}
__device__ __forceinline__ float bf2f(unsigned short h) {
    unsigned int u = ((unsigned int)h) << 16;
    return __builtin_bit_cast(float, u);
}
__device__ __forceinline__ float sigm(float x) {
    return __builtin_amdgcn_rcpf(1.0f + __builtin_amdgcn_exp2f(-1.44269504088896f * x));
}
__device__ __forceinline__ float tanh_f(float x) {
    float a = __builtin_fabsf(x);
    float e = __builtin_amdgcn_exp2f(-2.88539008177793f * a);  // exp(-2a)
    float t = (1.0f - e) * __builtin_amdgcn_rcpf(1.0f + e);
    return __builtin_copysignf(t, x);
}

__global__ __launch_bounds__(512, 2) void lstm2_kernel(
    const float* __restrict__ x,
    const float* __restrict__ wih0, const float* __restrict__ whh0,
    const float* __restrict__ bih0, const float* __restrict__ bhh0,
    const float* __restrict__ wih1, const float* __restrict__ whh1,
    const float* __restrict__ bih1, const float* __restrict__ bhh1,
    const float* __restrict__ fcw,  const float* __restrict__ fcb,
    float* __restrict__ out)
{
    // A-panels: rows 0-7 = bf16_hi(inp[b]), rows 8-15 = bf16_lo(inp[b]).
    // panel0 cols [0,64)=x_t, [64,128)=h_l0; panel1 cols [0,64)=h_l0(t), [64,128)=h_l1.
    __shared__ __align__(16) unsigned short panel0[16 * PSTR];
    __shared__ __align__(16) unsigned short panel1[16 * PSTR];
    __shared__ float gA[NB * GSTR];   // folded layer-0 gates
    __shared__ float gB[NB * GSTR];   // folded layer-1 gates
    __shared__ float bias0[256], bias1[256];
    __shared__ float h2buf[NB * 64];
    __shared__ float fcw_s[256];
    __shared__ float fcb_s[4];

    const int tid  = threadIdx.x;
    const int lane = tid & 63;
    const int wave = tid >> 6;              // 8 waves
    const int b0   = blockIdx.x * NB;

    for (int i = tid; i < 256; i += 512) {
        bias0[i] = bih0[i] + bhh0[i];
        bias1[i] = bih1[i] + bhh1[i];
        fcw_s[i] = fcw[i];
    }
    if (tid < 4) fcb_s[tid] = fcb[tid];
    for (int i = tid; i < 16 * PSTR; i += 512) { panel0[i] = 0; panel1[i] = 0; }

    // ---- Weight B-fragments in registers (resident all steps) ----
    // B layout: n = lane&15 within n-tile, k = (lane>>4)*8 + j.
    // Combined K=128: k<64 -> w_ih[n][k]; k>=64 -> w_hh[n][k-64].
    const int mrow = lane & 15;
    const int kg   = lane >> 4;
    short8 whi[2][2][4], wlo[2][2][4];      // [layer][n-tile][k-tile]
    #pragma unroll
    for (int l = 0; l < 2; ++l) {
        const float* wih = l ? wih1 : wih0;
        const float* whh = l ? whh1 : whh0;
        #pragma unroll
        for (int ni = 0; ni < 2; ++ni) {
            const int n = (wave * 2 + ni) * 16 + mrow;
            #pragma unroll
            for (int kt = 0; kt < 4; ++kt) {
                const int k0 = kt * 32 + kg * 8;
                const float* src = (k0 < 64) ? (wih + n * 64 + k0)
                                             : (whh + n * 64 + (k0 - 64));
                union { short8 s; unsigned short u[8]; } hi8, lo8;
                #pragma unroll
                for (int j = 0; j < 8; ++j) {
                    float w = src[j];
                    unsigned short h = f2bf(w);
                    hi8.u[j] = h;
                    lo8.u[j] = f2bf(w - bf2f(h));
                }
                whi[l][ni][kt] = hi8.s;
                wlo[l][ni][kt] = lo8.s;
            }
        }
    }

    __syncthreads();                        // panels zeroed
    const int bx = tid >> 6;                // x-stage mapping: batch
    const int kx = tid & 63;                // x-stage mapping: feature
    {
        float xv = x[((size_t)(b0 + bx) * T_SEQ + 0) * 64 + kx];
        unsigned short h = f2bf(xv);
        panel0[bx * PSTR + kx]       = h;
        panel0[(bx + 8) * PSTR + kx] = f2bf(xv - bf2f(h));
    }
    float c0 = 0.f, c1 = 0.f;               // cell state: thread owns (b=wave, h=lane)
    __syncthreads();

    const int b  = wave;
    const int hh = lane;
    const int n0 = wave * 32 + mrow;        // C columns this lane stores
    const int n1 = n0 + 16;

    // Merged pipeline: iteration s computes L0 gates for step s (s<T) and
    // L1 gates for step s-1 (s>=1) in ONE MFMA phase, then both cell updates
    // in ONE elementwise phase. 2 barriers per iteration, T+1 iterations.
    for (int s = 0; s <= T_SEQ; ++s) {
        const int tn = (s + 1 < T_SEQ) ? (s + 1) : (T_SEQ - 1);
        float xv = x[((size_t)(b0 + bx) * T_SEQ + tn) * 64 + kx];  // prefetch x(s+1)

        // ---- Merged MFMA phase: panel0 -> gA (L0, step s), panel1 -> gB (L1, step s-1)
        short8 af0[4], af1[4];
        #pragma unroll
        for (int kt = 0; kt < 4; ++kt) {    // A[m][kt*32 + kg*8 + j], 16B aligned
            af0[kt] = *(const short8*)(panel0 + mrow * PSTR + kt * 32 + kg * 8);
            af1[kt] = *(const short8*)(panel1 + mrow * PSTR + kt * 32 + kg * 8);
        }
        float4v c00 = {0.f,0.f,0.f,0.f}, c01 = {0.f,0.f,0.f,0.f};
        float4v c10 = {0.f,0.f,0.f,0.f}, c11 = {0.f,0.f,0.f,0.f};
        #pragma unroll
        for (int kt = 0; kt < 4; ++kt) {    // pass 1: W_hi (4 indep chains)
            c00 = __builtin_amdgcn_mfma_f32_16x16x32_bf16(af0[kt], whi[0][0][kt], c00, 0, 0, 0);
            c01 = __builtin_amdgcn_mfma_f32_16x16x32_bf16(af0[kt], whi[0][1][kt], c01, 0, 0, 0);
            c10 = __builtin_amdgcn_mfma_f32_16x16x32_bf16(af1[kt], whi[1][0][kt], c10, 0, 0, 0);
            c11 = __builtin_amdgcn_mfma_f32_16x16x32_bf16(af1[kt], whi[1][1][kt], c11, 0, 0, 0);
        }
        #pragma unroll
        for (int kt = 0; kt < 4; ++kt) {    // pass 2: W_lo
            c00 = __builtin_amdgcn_mfma_f32_16x16x32_bf16(af0[kt], wlo[0][0][kt], c00, 0, 0, 0);
            c01 = __builtin_amdgcn_mfma_f32_16x16x32_bf16(af0[kt], wlo[0][1][kt], c01, 0, 0, 0);
            c10 = __builtin_amdgcn_mfma_f32_16x16x32_bf16(af1[kt], wlo[1][0][kt], c10, 0, 0, 0);
            c11 = __builtin_amdgcn_mfma_f32_16x16x32_bf16(af1[kt], wlo[1][1][kt], c11, 0, 0, 0);
        }
        // Fold hi+lo A-rows in-register: C row m (lanes 0-31) += C row m+8 (lanes 32-63).
        // C/D layout: col = lane&15, row = (lane>>4)*4 + r  [measured m89/m91]
        #pragma unroll
        for (int r = 0; r < 4; ++r) {
            float v00 = c00[r] + __shfl_xor(c00[r], 32, 64);
            float v01 = c01[r] + __shfl_xor(c01[r], 32, 64);
            float v10 = c10[r] + __shfl_xor(c10[r], 32, 64);
            float v11 = c11[r] + __shfl_xor(c11[r], 32, 64);
            if (lane < 32) {                // kg in {0,1}: batch row = kg*4 + r
                const int br = kg * 4 + r;
                gA[br * GSTR + n0] = v00;
                gA[br * GSTR + n1] = v01;
                gB[br * GSTR + n0] = v10;
                gB[br * GSTR + n1] = v11;
            }
        }
        __syncthreads();

        // ---- Merged elementwise phase ----
        if (s < T_SEQ) {                    // layer-0 cell update, step s
            float gi = gA[b * GSTR + hh]       + bias0[hh];
            float gf = gA[b * GSTR + 64 + hh]  + bias0[64 + hh];
            float gg = gA[b * GSTR + 128 + hh] + bias0[128 + hh];
            float go = gA[b * GSTR + 192 + hh] + bias0[192 + hh];
            float ig = sigm(gi), fg = sigm(gf), gt = tanh_f(gg), og = sigm(go);
            c0 = fg * c0 + ig * gt;
            float hv = og * tanh_f(c0);
            unsigned short hhi = f2bf(hv);
            unsigned short hlo = f2bf(hv - bf2f(hhi));
            panel0[b * PSTR + 64 + hh]       = hhi;   // layer-0 recurrence
            panel0[(b + 8) * PSTR + 64 + hh] = hlo;
            panel1[b * PSTR + hh]            = hhi;   // layer-1 input h1(s)
            panel1[(b + 8) * PSTR + hh]      = hlo;
            unsigned short xh = f2bf(xv);              // stage x(s+1)
            panel0[bx * PSTR + kx]       = xh;
            panel0[(bx + 8) * PSTR + kx] = f2bf(xv - bf2f(xh));
        }
        if (s > 0) {                        // layer-1 cell update, step s-1
            float gi = gB[b * GSTR + hh]       + bias1[hh];
            float gf = gB[b * GSTR + 64 + hh]  + bias1[64 + hh];
            float gg = gB[b * GSTR + 128 + hh] + bias1[128 + hh];
            float go = gB[b * GSTR + 192 + hh] + bias1[192 + hh];
            float ig = sigm(gi), fg = sigm(gf), gt = tanh_f(gg), og = sigm(go);
            c1 = fg * c1 + ig * gt;
            float hv = og * tanh_f(c1);
            unsigned short hhi = f2bf(hv);
            unsigned short hlo = f2bf(hv - bf2f(hhi));
            panel1[b * PSTR + 64 + hh]       = hhi;   // layer-1 recurrence
            panel1[(b + 8) * PSTR + 64 + hh] = hlo;
            if (s == T_SEQ) h2buf[b * 64 + hh] = hv;
        }
        __syncthreads();
    }

    // ---- FC head: out[b][nc] = h2_last[b] . fc_w[nc] + fc_b[nc] ----
    if (tid < 32) {
        const int bb = tid >> 2;
        const int nc = tid & 3;
        float s = fcb_s[nc];
        #pragma unroll 8
        for (int h = 0; h < 64; ++h) s += h2buf[bb * 64 + h] * fcw_s[nc * 64 + h];
        out[(size_t)(b0 + bb) * 4 + nc] = s;
    }
}

extern "C" void kernel_launch(void* const* d_in, const int* in_sizes, int n_in,
                              void* d_out, int out_size, void* d_ws, size_t ws_size,
                              hipStream_t stream) {
    const float* x    = (const float*)d_in[0];
    const float* wih0 = (const float*)d_in[1];
    const float* whh0 = (const float*)d_in[2];
    const float* bih0 = (const float*)d_in[3];
    const float* bhh0 = (const float*)d_in[4];
    const float* wih1 = (const float*)d_in[5];
    const float* whh1 = (const float*)d_in[6];
    const float* bih1 = (const float*)d_in[7];
    const float* bhh1 = (const float*)d_in[8];
    const float* fcw  = (const float*)d_in[9];
    const float* fcb  = (const float*)d_in[10];
    float* out = (float*)d_out;
    (void)d_ws; (void)ws_size; (void)in_sizes; (void)n_in; (void)out_size;

    lstm2_kernel<<<dim3(2048 / NB), dim3(512), 0, stream>>>(
        x, wih0, whh0, bih0, bhh0, wih1, whh1, bih1, bhh1, fcw, fcb, out);
}

// Round 3
// 920.187 us; speedup vs baseline: 1.1715x; 1.1715x over previous
//
#include <hip/hip_runtime.h>
#include <stdint.h>

// LSTMNet: B=2048, T=512, IN=64, H=64, 4H=256, 2 layers, FC to 4 classes.
// R3: 256 WGs x 512 threads; wave-specialized by layer (waves 0-3 = L0,
// waves 4-7 = L1 lagging one step). Each wave owns ALL FOUR gate n-tiles for
// one 16-wide h-slice => gates for (b,h) land in one lane; gate LDS buffer
// eliminated. hi/lo-in-M fold via ds_bpermute(lane^32); kg-halves then take
// disjoint r-pairs (no duplicated cell math; 2 cells/lane in registers).
// Weights resident as B-frags (W_hi + W_lo bf16 split = fp32-grade).

#define T_SEQ 512
#define NB    8
#define PSTR  136          // A-panel row stride (bf16): 272B, 16B-aligned b128

typedef __attribute__((ext_vector_type(8))) short  short8;   // 8 x bf16
typedef __attribute__((ext_vector_type(4))) float  float4v;  // MFMA C/D

__device__ __forceinline__ unsigned short f2bf(float f) {
    unsigned int u = __builtin_bit_cast(unsigned int, f);
    return (unsigned short)((u + 0x7FFFu + ((u >> 16) & 1u)) >> 16);  // RNE
}
__device__ __forceinline__ float bf2f(unsigned short h) {
    unsigned int u = ((unsigned int)h) << 16;
    return __builtin_bit_cast(float, u);
}
__device__ __forceinline__ float sigm(float x) {
    return __builtin_amdgcn_rcpf(1.0f + __builtin_amdgcn_exp2f(-1.44269504088896f * x));
}
__device__ __forceinline__ float tanh_f(float x) {
    float a = __builtin_fabsf(x);
    float e = __builtin_amdgcn_exp2f(-2.88539008177793f * a);  // exp(-2a)
    float t = (1.0f - e) * __builtin_amdgcn_rcpf(1.0f + e);
    return __builtin_copysignf(t, x);
}
__device__ __forceinline__ float permx32(float v) {
    int p = __builtin_amdgcn_ds_bpermute((int)((threadIdx.x & 63) ^ 32) << 2,
                                         __builtin_bit_cast(int, v));
    return __builtin_bit_cast(float, p);
}

__global__ __launch_bounds__(512, 2) void lstm2_kernel(
    const float* __restrict__ x,
    const float* __restrict__ wih0, const float* __restrict__ whh0,
    const float* __restrict__ bih0, const float* __restrict__ bhh0,
    const float* __restrict__ wih1, const float* __restrict__ whh1,
    const float* __restrict__ bih1, const float* __restrict__ bhh1,
    const float* __restrict__ fcw,  const float* __restrict__ fcb,
    float* __restrict__ out)
{
    // A-panels: rows 0-7 = bf16_hi(inp[b]), rows 8-15 = bf16_lo(inp[b]).
    // panel0: cols [0,64)=x_t, [64,128)=h_l0.  panel1: [0,64)=h_l0, [64,128)=h_l1.
    __shared__ __align__(16) unsigned short panel0[16 * PSTR];
    __shared__ __align__(16) unsigned short panel1[16 * PSTR];
    __shared__ float h2buf[NB * 64];
    __shared__ float fcw_s[256];
    __shared__ float fcb_s[4];

    const int tid  = threadIdx.x;
    const int lane = tid & 63;
    const int wave = tid >> 6;
    const int mrow = lane & 15;         // A/C m-row index base & C col-within-tile
    const int kg   = lane >> 4;         // k-quad / C row-group
    const int lset = wave >> 2;         // 0 = layer-0 waves, 1 = layer-1 waves
    const int ws   = wave & 3;          // h-slice [16*ws, 16*ws+16)
    const int b0   = blockIdx.x * NB;

    for (int i = tid; i < 256; i += 512) fcw_s[i] = fcw[i];
    if (tid < 4) fcb_s[tid] = fcb[tid];
    for (int i = tid; i < 16 * PSTR; i += 512) { panel0[i] = 0; panel1[i] = 0; }

    const float* wih  = lset ? wih1 : wih0;
    const float* whh  = lset ? whh1 : whh0;
    const float* bihp = lset ? bih1 : bih0;
    const float* bhhp = lset ? bhh1 : bhh0;

    // Per-lane gate biases: gate g at n = g*64 + ws*16 + mrow.
    float biasg[4];
    #pragma unroll
    for (int g = 0; g < 4; ++g) {
        const int idx = g * 64 + ws * 16 + mrow;
        biasg[g] = bihp[idx] + bhhp[idx];
    }

    // Weight B-frags: wave owns n-tiles {ws, 4+ws, 8+ws, 12+ws} = gates i,f,g,o
    // of its h-slice. B layout: n = tile*16 + (lane&15), k = kg*8 + j (per kt).
    // Combined K=128: k<64 -> w_ih[n][k]; k>=64 -> w_hh[n][k-64].
    short8 whiF[4][4], wloF[4][4];      // [gate][k-tile] = 128 VGPRs
    #pragma unroll
    for (int g = 0; g < 4; ++g) {
        const int n = (g * 4 + ws) * 16 + mrow;
        #pragma unroll
        for (int kt = 0; kt < 4; ++kt) {
            const int k0 = kt * 32 + kg * 8;
            const float* src = (k0 < 64) ? (wih + n * 64 + k0)
                                         : (whh + n * 64 + (k0 - 64));
            union { short8 s; unsigned short u[8]; } hi8, lo8;
            #pragma unroll
            for (int j = 0; j < 8; ++j) {
                float w = src[j];
                unsigned short h = f2bf(w);
                hi8.u[j] = h;
                lo8.u[j] = f2bf(w - bf2f(h));
            }
            whiF[g][kt] = hi8.s;
            wloF[g][kt] = lo8.s;
        }
    }

    __syncthreads();                    // panels zeroed
    const int bx = tid >> 6;            // x-stage mapping: batch
    const int kx = tid & 63;            // x-stage mapping: feature
    {
        float xv = x[((size_t)(b0 + bx) * T_SEQ + 0) * 64 + kx];
        unsigned short h = f2bf(xv);
        panel0[bx * PSTR + kx]       = h;
        panel0[(bx + 8) * PSTR + kx] = f2bf(xv - bf2f(h));
    }
    __syncthreads();

    const unsigned short* mypanel = lset ? panel1 : panel0;
    // This lane's two cells: r in {rsel, rsel+1}, b = (kg&1)*4 + r.
    const int bA   = ((kg & 1) << 2) + ((kg >> 1) << 1);
    const int bB   = bA + 1;
    const int hcol = ws * 16 + mrow;
    float cA = 0.f, cB = 0.f;

    // Iteration s: MFMA computes L0 gates(step s) on waves 0-3 and L1 gates
    // (step s-1) on waves 4-7; cell phase updates both. 2 barriers/iter.
    for (int s = 0; s <= T_SEQ; ++s) {
        const int tn = (s + 1 < T_SEQ) ? (s + 1) : (T_SEQ - 1);
        float xv = x[((size_t)(b0 + bx) * T_SEQ + tn) * 64 + kx];  // prefetch

        // ---- MFMA phase: 4 gate chains, W_hi then W_lo pass ----
        short8 af[4];
        #pragma unroll
        for (int kt = 0; kt < 4; ++kt)
            af[kt] = *(const short8*)(mypanel + mrow * PSTR + kt * 32 + kg * 8);
        float4v acc[4];
        #pragma unroll
        for (int g = 0; g < 4; ++g) acc[g] = (float4v){0.f, 0.f, 0.f, 0.f};
        #pragma unroll
        for (int kt = 0; kt < 4; ++kt) {
            #pragma unroll
            for (int g = 0; g < 4; ++g)
                acc[g] = __builtin_amdgcn_mfma_f32_16x16x32_bf16(af[kt], whiF[g][kt], acc[g], 0, 0, 0);
        }
        #pragma unroll
        for (int kt = 0; kt < 4; ++kt) {
            #pragma unroll
            for (int g = 0; g < 4; ++g)
                acc[g] = __builtin_amdgcn_mfma_f32_16x16x32_bf16(af[kt], wloF[g][kt], acc[g], 0, 0, 0);
        }
        __syncthreads();    // panel reads done; cell phase may overwrite

        // ---- Cell phase ----
        const bool active = lset ? (s > 0) : (s < T_SEQ);
        if (active) {       // wave-uniform branch
            // Fold hi+lo products: C row m (kg<2) + row m+8 (kg>=2) via lane^32.
            // C/D: col = lane&15, row = kg*4 + r  [measured m89/m91].
            float gA4[4], gB4[4];
            #pragma unroll
            for (int g = 0; g < 4; ++g) {
                float s0 = acc[g][0] + permx32(acc[g][0]);
                float s1 = acc[g][1] + permx32(acc[g][1]);
                float s2 = acc[g][2] + permx32(acc[g][2]);
                float s3 = acc[g][3] + permx32(acc[g][3]);
                gA4[g] = ((kg & 2) ? s2 : s0) + biasg[g];
                gB4[g] = ((kg & 2) ? s3 : s1) + biasg[g];
            }
            // Cell A
            {
                float ig = sigm(gA4[0]), fg = sigm(gA4[1]);
                float gt = tanh_f(gA4[2]), og = sigm(gA4[3]);
                cA = fg * cA + ig * gt;
                float hv = og * tanh_f(cA);
                unsigned short hhi = f2bf(hv);
                unsigned short hlo = f2bf(hv - bf2f(hhi));
                if (lset == 0) {
                    panel0[bA * PSTR + 64 + hcol]       = hhi;  // L0 recurrence
                    panel0[(bA + 8) * PSTR + 64 + hcol] = hlo;
                    panel1[bA * PSTR + hcol]            = hhi;  // L1 input
                    panel1[(bA + 8) * PSTR + hcol]      = hlo;
                } else {
                    panel1[bA * PSTR + 64 + hcol]       = hhi;  // L1 recurrence
                    panel1[(bA + 8) * PSTR + 64 + hcol] = hlo;
                    if (s == T_SEQ) h2buf[bA * 64 + hcol] = hv;
                }
            }
            // Cell B
            {
                float ig = sigm(gB4[0]), fg = sigm(gB4[1]);
                float gt = tanh_f(gB4[2]), og = sigm(gB4[3]);
                cB = fg * cB + ig * gt;
                float hv = og * tanh_f(cB);
                unsigned short hhi = f2bf(hv);
                unsigned short hlo = f2bf(hv - bf2f(hhi));
                if (lset == 0) {
                    panel0[bB * PSTR + 64 + hcol]       = hhi;
                    panel0[(bB + 8) * PSTR + 64 + hcol] = hlo;
                    panel1[bB * PSTR + hcol]            = hhi;
                    panel1[(bB + 8) * PSTR + hcol]      = hlo;
                } else {
                    panel1[bB * PSTR + 64 + hcol]       = hhi;
                    panel1[(bB + 8) * PSTR + 64 + hcol] = hlo;
                    if (s == T_SEQ) h2buf[bB * 64 + hcol] = hv;
                }
            }
        }
        if (s < T_SEQ) {    // stage x(s+1) into panel0
            unsigned short xh = f2bf(xv);
            panel0[bx * PSTR + kx]       = xh;
            panel0[(bx + 8) * PSTR + kx] = f2bf(xv - bf2f(xh));
        }
        __syncthreads();
    }

    // ---- FC head: out[b][nc] = h2_last[b] . fc_w[nc] + fc_b[nc] ----
    if (tid < 32) {
        const int bb = tid >> 2;
        const int nc = tid & 3;
        float s = fcb_s[nc];
        #pragma unroll 8
        for (int h = 0; h < 64; ++h) s += h2buf[bb * 64 + h] * fcw_s[nc * 64 + h];
        out[(size_t)(b0 + bb) * 4 + nc] = s;
    }
}

extern "C" void kernel_launch(void* const* d_in, const int* in_sizes, int n_in,
                              void* d_out, int out_size, void* d_ws, size_t ws_size,
                              hipStream_t stream) {
    const float* x    = (const float*)d_in[0];
    const float* wih0 = (const float*)d_in[1];
    const float* whh0 = (const float*)d_in[2];
    const float* bih0 = (const float*)d_in[3];
    const float* bhh0 = (const float*)d_in[4];
    const float* wih1 = (const float*)d_in[5];
    const float* whh1 = (const float*)d_in[6];
    const float* bih1 = (const float*)d_in[7];
    const float* bhh1 = (const float*)d_in[8];
    const float* fcw  = (const float*)d_in[9];
    const float* fcb  = (const float*)d_in[10];
    float* out = (float*)d_out;
    (void)d_ws; (void)ws_size; (void)in_sizes; (void)n_in; (void)out_size;

    lstm2_kernel<<<dim3(2048 / NB), dim3(512), 0, stream>>>(
        x, wih0, whh0, bih0, bhh0, wih1, whh1, bih1, bhh1, fcw, fcb, out);
}

// Round 4
// 797.107 us; speedup vs baseline: 1.3524x; 1.1544x over previous
//
#include <hip/hip_runtime.h>
#include <stdint.h>

// LSTMNet: B=2048, T=512, IN=64, H=64, 4H=256, 2 layers, FC to 4 classes.
// R4: 512 WGs x 512 threads, NB=4 batches/WG => 2 blocks/CU (the key change:
// co-resident blocks hide each other's barrier/latency stalls).
// Register fit via W=bf16 (hi only, 64 VGPRs); A-side keeps hi/lo-in-M split
// (free in idle M rows): error ~1e-3, threshold 3.16e-3.
// Ping-pong panels => ONE barrier/iter. Wave-specialized: waves 0-3 L0,
// waves 4-7 L1 (lagging one step). 4 indep depth-4 MFMA chains/wave.
// Batch m-rows: b0->0, b1->1, b2->4, b3->5 (hi), +8 (lo) so the lane^32 fold
// leaves one cell on every lane (kg0->b0, kg2->b1, kg1->b2, kg3->b3).

#define T_SEQ 512
#define NB    4
#define PSTR  136          // A-panel row stride (bf16): 272B, 16B-aligned b128

typedef __attribute__((ext_vector_type(8))) short  short8;   // 8 x bf16
typedef __attribute__((ext_vector_type(4))) float  float4v;  // MFMA C/D

__device__ __forceinline__ unsigned short f2bf(float f) {
    unsigned int u = __builtin_bit_cast(unsigned int, f);
    return (unsigned short)((u + 0x7FFFu + ((u >> 16) & 1u)) >> 16);  // RNE
}
__device__ __forceinline__ float bf2f(unsigned short h) {
    unsigned int u = ((unsigned int)h) << 16;
    return __builtin_bit_cast(float, u);
}
__device__ __forceinline__ float sigm(float x) {
    return __builtin_amdgcn_rcpf(1.0f + __builtin_amdgcn_exp2f(-1.44269504088896f * x));
}
__device__ __forceinline__ float tanh_f(float x) {
    float a = __builtin_fabsf(x);
    float e = __builtin_amdgcn_exp2f(-2.88539008177793f * a);  // exp(-2a)
    float t = (1.0f - e) * __builtin_amdgcn_rcpf(1.0f + e);
    return __builtin_copysignf(t, x);
}
__device__ __forceinline__ float permx32(float v) {
    int p = __builtin_amdgcn_ds_bpermute((int)((threadIdx.x & 63) ^ 32) << 2,
                                         __builtin_bit_cast(int, v));
    return __builtin_bit_cast(float, p);
}

__global__ __launch_bounds__(512, 4) void lstm2_kernel(
    const float* __restrict__ x,
    const float* __restrict__ wih0, const float* __restrict__ whh0,
    const float* __restrict__ bih0, const float* __restrict__ bhh0,
    const float* __restrict__ wih1, const float* __restrict__ whh1,
    const float* __restrict__ bih1, const float* __restrict__ bhh1,
    const float* __restrict__ fcw,  const float* __restrict__ fcb,
    float* __restrict__ out)
{
    // Ping-pong A-panels. panel0: cols [0,64)=x_t, [64,128)=h_l0.
    // panel1: cols [0,64)=h_l0(t), [64,128)=h_l1. Rows: hi {0,1,4,5}, lo +8.
    __shared__ __align__(16) unsigned short panel0[2][16 * PSTR];
    __shared__ __align__(16) unsigned short panel1[2][16 * PSTR];
    __shared__ float h2buf[NB * 64];
    __shared__ float fcw_s[256];
    __shared__ float fcb_s[4];

    const int tid  = threadIdx.x;
    const int lane = tid & 63;
    const int wave = tid >> 6;
    const int mrow = lane & 15;         // A m-row base / B n-within-tile / C col
    const int kg   = lane >> 4;         // k-quad / C row-group
    const int lset = wave >> 2;         // 0 = layer-0 waves, 1 = layer-1 waves
    const int ws   = wave & 3;          // h-slice [16*ws, 16*ws+16)
    const int b0   = blockIdx.x * NB;

    for (int i = tid; i < 256; i += 512) fcw_s[i] = fcw[i];
    if (tid < 4) fcb_s[tid] = fcb[tid];
    for (int i = tid; i < 2 * 16 * PSTR; i += 512) {
        panel0[0][i] = 0; panel1[0][i] = 0;   // flattened across both buffers
    }

    const float* wih  = lset ? wih1 : wih0;
    const float* whh  = lset ? whh1 : whh0;
    const float* bihp = lset ? bih1 : bih0;
    const float* bhhp = lset ? bhh1 : bhh0;

    // Per-lane gate biases: gate g at n = g*64 + ws*16 + mrow.
    float biasg[4];
    #pragma unroll
    for (int g = 0; g < 4; ++g) {
        const int idx = g * 64 + ws * 16 + mrow;
        biasg[g] = bihp[idx] + bhhp[idx];
    }

    // Weight B-frags (bf16 hi only): wave owns n-tiles {ws,4+ws,8+ws,12+ws}
    // = gates i,f,g,o of its slice. n = tile*16 + mrow, k = kt*32 + kg*8 + j.
    // Combined K=128: k<64 -> w_ih[n][k]; k>=64 -> w_hh[n][k-64].
    short8 whiF[4][4];                  // 64 VGPRs
    #pragma unroll
    for (int g = 0; g < 4; ++g) {
        const int n = (g * 4 + ws) * 16 + mrow;
        #pragma unroll
        for (int kt = 0; kt < 4; ++kt) {
            const int k0 = kt * 32 + kg * 8;
            const float* src = (k0 < 64) ? (wih + n * 64 + k0)
                                         : (whh + n * 64 + (k0 - 64));
            union { short8 s; unsigned short u[8]; } hi8;
            #pragma unroll
            for (int j = 0; j < 8; ++j) hi8.u[j] = f2bf(src[j]);
            whiF[g][kt] = hi8.s;
        }
    }

    __syncthreads();                    // panels zeroed
    if (tid < 256) {                    // stage x(0) into panel0[0]
        const int bx = tid >> 6, kx = tid & 63;
        const int xr = (bx & 1) + ((bx & 2) << 1);      // {0,1,4,5}
        float xv = x[((size_t)(b0 + bx) * T_SEQ + 0) * 64 + kx];
        unsigned short h = f2bf(xv);
        panel0[0][xr * PSTR + kx]       = h;
        panel0[0][(xr + 8) * PSTR + kx] = f2bf(xv - bf2f(h));
    }
    __syncthreads();

    // This lane's cell: batch + rows (see header comment).
    const int bcell = ((kg & 1) << 1) | (kg >> 1);      // kg0->0,kg1->2,kg2->1,kg3->3
    const int hrow  = (bcell & 1) + ((bcell & 2) << 1); // {0,1,4,5}
    const int hcol  = ws * 16 + mrow;
    const int xrow  = (wave & 1) + ((wave & 2) << 1);   // x-stage row for L0 wave
    float c = 0.f;

    for (int s = 0; s <= T_SEQ; ++s) {
        const int p = s & 1;
        const unsigned short* rd = lset ? panel1[p] : panel0[p];
        unsigned short* wr0 = panel0[p ^ 1];
        unsigned short* wr1 = panel1[p ^ 1];

        float xv = 0.f;                 // prefetch x(s+1) (L0 waves only)
        if (lset == 0 && s < T_SEQ) {
            const int tn = (s + 1 < T_SEQ) ? (s + 1) : (T_SEQ - 1);
            xv = x[((size_t)(b0 + wave) * T_SEQ + tn) * 64 + lane];
        }

        // ---- MFMA: 4 gate chains, depth 4 ----
        short8 af[4];
        #pragma unroll
        for (int kt = 0; kt < 4; ++kt)
            af[kt] = *(const short8*)(rd + mrow * PSTR + kt * 32 + kg * 8);
        float4v acc[4];
        #pragma unroll
        for (int g = 0; g < 4; ++g) acc[g] = (float4v){0.f, 0.f, 0.f, 0.f};
        #pragma unroll
        for (int kt = 0; kt < 4; ++kt) {
            #pragma unroll
            for (int g = 0; g < 4; ++g)
                acc[g] = __builtin_amdgcn_mfma_f32_16x16x32_bf16(af[kt], whiF[g][kt], acc[g], 0, 0, 0);
        }

        // ---- Cell phase (writes go to the OTHER buffer; 1 barrier/iter) ----
        const bool active = lset ? (s > 0) : (s < T_SEQ);
        if (active) {                   // wave-uniform
            // Fold hi+lo A-rows: C row m + row m+8 via lane^32.
            // C/D: col = lane&15, row = kg*4 + r  [measured m89/m91].
            float gate[4];
            #pragma unroll
            for (int g = 0; g < 4; ++g) {
                float f0 = acc[g][0] + permx32(acc[g][0]);
                float f1 = acc[g][1] + permx32(acc[g][1]);
                gate[g] = ((kg & 2) ? f1 : f0) + biasg[g];
            }
            float ig = sigm(gate[0]), fg = sigm(gate[1]);
            float gt = tanh_f(gate[2]), og = sigm(gate[3]);
            c = fg * c + ig * gt;
            float hv = og * tanh_f(c);
            unsigned short hhi = f2bf(hv);
            unsigned short hlo = f2bf(hv - bf2f(hhi));
            if (lset == 0) {
                wr0[hrow * PSTR + 64 + hcol]       = hhi;  // L0 recurrence
                wr0[(hrow + 8) * PSTR + 64 + hcol] = hlo;
                wr1[hrow * PSTR + hcol]            = hhi;  // L1 input
                wr1[(hrow + 8) * PSTR + hcol]      = hlo;
            } else {
                wr1[hrow * PSTR + 64 + hcol]       = hhi;  // L1 recurrence
                wr1[(hrow + 8) * PSTR + 64 + hcol] = hlo;
                if (s == T_SEQ) h2buf[bcell * 64 + hcol] = hv;
            }
        }
        if (lset == 0 && s < T_SEQ) {   // stage x(s+1)
            unsigned short xh = f2bf(xv);
            wr0[xrow * PSTR + lane]       = xh;
            wr0[(xrow + 8) * PSTR + lane] = f2bf(xv - bf2f(xh));
        }
        __syncthreads();
    }

    // ---- FC head ----
    if (tid < 16) {
        const int bb = tid >> 2, nc = tid & 3;
        float s = fcb_s[nc];
        #pragma unroll 8
        for (int h = 0; h < 64; ++h) s += h2buf[bb * 64 + h] * fcw_s[nc * 64 + h];
        out[(size_t)(b0 + bb) * 4 + nc] = s;
    }
}

extern "C" void kernel_launch(void* const* d_in, const int* in_sizes, int n_in,
                              void* d_out, int out_size, void* d_ws, size_t ws_size,
                              hipStream_t stream) {
    const float* x    = (const float*)d_in[0];
    const float* wih0 = (const float*)d_in[1];
    const float* whh0 = (const float*)d_in[2];
    const float* bih0 = (const float*)d_in[3];
    const float* bhh0 = (const float*)d_in[4];
    const float* wih1 = (const float*)d_in[5];
    const float* whh1 = (const float*)d_in[6];
    const float* bih1 = (const float*)d_in[7];
    const float* bhh1 = (const float*)d_in[8];
    const float* fcw  = (const float*)d_in[9];
    const float* fcb  = (const float*)d_in[10];
    float* out = (float*)d_out;
    (void)d_ws; (void)ws_size; (void)in_sizes; (void)n_in; (void)out_size;

    lstm2_kernel<<<dim3(2048 / NB), dim3(512), 0, stream>>>(
        x, wih0, whh0, bih0, bhh0, wih1, whh1, bih1, bhh1, fcw, fcb, out);
}